// Round 9
// baseline (470.207 us; speedup 1.0000x reference)
//
#include <hip/hip_runtime.h>
#include <hip/hip_bf16.h>

typedef __attribute__((ext_vector_type(8))) short bf16x8;
typedef __attribute__((ext_vector_type(4))) float f32x4;
typedef unsigned short u16;

__device__ __forceinline__ u16 f2b(float f) {
  __hip_bfloat16 h = __float2bfloat16(f);
  return __builtin_bit_cast(unsigned short, h);
}
__device__ __forceinline__ float b2f(u16 u) {
  __hip_bfloat16 h = __builtin_bit_cast(__hip_bfloat16, u);
  return __bfloat162float(h);
}

#define BAR() __builtin_amdgcn_s_barrier()
#define LGKM0() do { asm volatile("s_waitcnt lgkmcnt(0)" ::: "memory"); __builtin_amdgcn_sched_barrier(0); } while (0)
#define LGKM4() do { asm volatile("s_waitcnt lgkmcnt(4)" ::: "memory"); __builtin_amdgcn_sched_barrier(0); } while (0)
#define LGKM8() do { asm volatile("s_waitcnt lgkmcnt(8)" ::: "memory"); __builtin_amdgcn_sched_barrier(0); } while (0)
#define VMCNT4() asm volatile("s_waitcnt vmcnt(4)" ::: "memory")
#define VMCNT2() asm volatile("s_waitcnt vmcnt(2)" ::: "memory")
#define VMCNT0() asm volatile("s_waitcnt vmcnt(0)" ::: "memory")

#define EPI_HID 0
#define EPI_QK 1
#define EPI_OUT 4

// ---------- 128^2 2-phase kernel (QK: N=128; OUT: N=512) ----------
__device__ __forceinline__ void stage_tile(char* sbase, const char* gbase, int ld_bytes, int tid) {
#pragma unroll
  for (int i = 0; i < 4; ++i) {
    int o = (i * 256 + tid) * 16;
    int row = o >> 7;
    int cb = o & 127;
    int scb = cb ^ ((row & 7) << 4);
    const char* src = gbase + (long)row * ld_bytes + scb;
    __builtin_amdgcn_global_load_lds((const __attribute__((address_space(1))) void*)src,
                                     (__attribute__((address_space(3))) void*)(sbase + o),
                                     16, 0, 0);
  }
}

template <int EPI>
__global__ __launch_bounds__(256, 2) void gemm_tn(
    const char* Ab, const char* Bb, long sAbat, long sBbat,
    int lda_b, int ldb_b, int nkt,
    u16* o0, u16* o1,
    const float* a0, const float* a1, const float* a2, const float* a3,
    float* fout, const float* xres) {
  __shared__ __align__(16) char lds[32768];
  char* sA = lds;
  char* sB = lds + 16384;
  const int tid = threadIdx.x;
  const int lane = tid & 63;
  const int wave = tid >> 6;
  const int wm = wave >> 1, wn = wave & 1;
  const int l16 = lane & 15, lq = lane >> 4;
  const int bat = blockIdx.z;
  const int row0 = blockIdx.y * 128;
  const int col0 = blockIdx.x * 128;

  const char* Abase = Ab + (long)bat * sAbat + (long)row0 * lda_b;
  const char* Bbase = Bb + (long)bat * sBbat + (long)col0 * ldb_b;

  f32x4 acc[4][4];
#pragma unroll
  for (int i = 0; i < 4; ++i)
#pragma unroll
    for (int j = 0; j < 4; ++j) acc[i][j] = (f32x4){0.f, 0.f, 0.f, 0.f};

  for (int kt = 0; kt < nkt; ++kt) {
    stage_tile(sA, Abase + (long)kt * 128, lda_b, tid);
    stage_tile(sB, Bbase + (long)kt * 128, ldb_b, tid);
    __syncthreads();
#pragma unroll
    for (int kk = 0; kk < 2; ++kk) {
      bf16x8 af[4], bfr[4];
#pragma unroll
      for (int mf = 0; mf < 4; ++mf) {
        int r = wm * 64 + mf * 16 + l16;
        int kb = kk * 64 + lq * 16;
        af[mf] = *(const bf16x8*)(sA + r * 128 + (kb ^ ((r & 7) << 4)));
      }
#pragma unroll
      for (int nf = 0; nf < 4; ++nf) {
        int r = wn * 64 + nf * 16 + l16;
        int kb = kk * 64 + lq * 16;
        bfr[nf] = *(const bf16x8*)(sB + r * 128 + (kb ^ ((r & 7) << 4)));
      }
#pragma unroll
      for (int mf = 0; mf < 4; ++mf)
#pragma unroll
        for (int nf = 0; nf < 4; ++nf)
          acc[mf][nf] = __builtin_amdgcn_mfma_f32_16x16x32_bf16(af[mf], bfr[nf], acc[mf][nf], 0, 0, 0);
    }
    __syncthreads();
  }

#pragma unroll
  for (int mf = 0; mf < 4; ++mf) {
#pragma unroll
    for (int nf = 0; nf < 4; ++nf) {
      const int row = row0 + wm * 64 + mf * 16 + lq * 4;
      const int col = col0 + wn * 64 + nf * 16 + l16;
      f32x4 v = acc[mf][nf];
      if constexpr (EPI == EPI_QK) {
        float qg = a0[col], qbt = a1[col], kg = a2[col], kbt = a3[col];
#pragma unroll
        for (int i = 0; i < 4; ++i) {
          float t = v[i];
          o0[(size_t)(row + i) * 128 + col] = f2b(t * qg + qbt);
          o1[(size_t)(row + i) * 128 + col] = f2b(t * kg + kbt);
        }
      } else if constexpr (EPI == EPI_OUT) {
        float bias = a0[col];
#pragma unroll
        for (int i = 0; i < 4; ++i)
          fout[(size_t)(row + i) * 512 + col] = v[i] + bias + xres[(size_t)(row + i) * 512 + col];
      }
    }
  }
}

// ---------- 256^2 16x16 minimal-barrier kernel (HID) — round-6 best ----------
__device__ __forceinline__ void stage_half(char* sbase, const char* gbase, long ld, int tid) {
#pragma unroll
  for (int i = 0; i < 2; ++i) {
    int o = (i * 512 + tid) * 16;
    int row = o >> 7;
    int cb = o & 127;
    int scb = cb ^ ((row & 7) << 4);
    const char* src = gbase + (long)row * ld + scb;
    __builtin_amdgcn_global_load_lds((const __attribute__((address_space(1))) void*)src,
                                     (__attribute__((address_space(3))) void*)(sbase + o),
                                     16, 0, 0);
  }
}

template <int EPI>
__global__ __launch_bounds__(512, 2) void gemm256(
    const char* Ab, const char* Bb, long sAbat, long sBbat,
    long lda, long ldb, int nkt, int nx,
    u16* o0, u16* o1,
    const float* a0, float* fout, const float* xres) {
  extern __shared__ __align__(16) char lds[];
  const int tid = threadIdx.x;
  const int lane = tid & 63;
  const int wave = tid >> 6;
  const int wm = wave >> 2;
  const int wn = wave & 3;
  const int l16 = lane & 15, lq = lane >> 4;
  const int bat = blockIdx.y;

  const int nwg = gridDim.x;
  const int qq = nwg >> 3;
  const int fid = blockIdx.x;
  const int swz = (fid & 7) * qq + (fid >> 3);
  const int row0 = (swz / nx) * 256;
  const int col0 = (swz % nx) * 256;

  const char* gA = Ab + (long)bat * sAbat + (long)row0 * lda;
  const char* gB = Bb + (long)bat * sBbat + (long)col0 * ldb;

  f32x4 acc[8][4];
#pragma unroll
  for (int i = 0; i < 8; ++i)
#pragma unroll
    for (int j = 0; j < 4; ++j) acc[i][j] = (f32x4){0.f, 0.f, 0.f, 0.f};

  const int kmask = (l16 & 7) << 4;
  const int kb0 = (lq * 16) ^ kmask;
  const int kb1 = (64 + lq * 16) ^ kmask;
  const int rB = (wn & 1) * 64;

  stage_half(lds + 32768, gB, ldb, tid);
  stage_half(lds + 32768 + 16384, gB + 128 * ldb, ldb, tid);
  stage_half(lds, gA, lda, tid);
  stage_half(lds + 16384, gA + 128 * lda, lda, tid);
  if (nkt > 1) {
    stage_half(lds + 65536 + 32768, gB + 128, ldb, tid);
    stage_half(lds + 65536 + 32768 + 16384, gB + 128 * ldb + 128, ldb, tid);
    VMCNT4();
  } else {
    VMCNT0();
  }
  BAR();

  bf16x8 af0[4], af1[4], afp0[4], afp1[4], bfr0[4], bfr1[4];
  {
    const char* myA = lds + wm * 16384;
    const char* myB = lds + 32768 + (wn >> 1) * 16384;
#pragma unroll
    for (int nf = 0; nf < 4; ++nf)
      bfr0[nf] = *(const bf16x8*)(myB + (rB + nf * 16 + l16) * 128 + kb0);
#pragma unroll
    for (int mf = 0; mf < 4; ++mf)
      af0[mf] = *(const bf16x8*)(myA + (mf * 16 + l16) * 128 + kb0);
  }

  for (int t = 0; t < nkt; ++t) {
    const char* bufc = lds + (t & 1) * 65536;
    const char* bufn = lds + ((t + 1) & 1) * 65536;
    const char* myA = bufc + wm * 16384;
    const char* myB = bufc + 32768 + (wn >> 1) * 16384;
    const char* nA = bufn + wm * 16384;
    const char* nB = bufn + 32768 + (wn >> 1) * 16384;
    char* stA = (char*)bufn;
    char* stB = (char*)bufc + 32768;
    const bool sA_ok = (t + 1) < nkt;
    const bool sB_ok = (t + 2) < nkt;

#pragma unroll
    for (int nf = 0; nf < 4; ++nf)
      bfr1[nf] = *(const bf16x8*)(myB + (rB + nf * 16 + l16) * 128 + kb1);
#pragma unroll
    for (int mf = 0; mf < 4; ++mf)
      af1[mf] = *(const bf16x8*)(myA + (mf * 16 + l16) * 128 + kb1);
    if (sA_ok) stage_half(stA, gA + (long)(t + 1) * 128, lda, tid);
    LGKM8();
    __builtin_amdgcn_s_setprio(1);
#pragma unroll
    for (int mf = 0; mf < 4; ++mf)
#pragma unroll
      for (int nf = 0; nf < 4; ++nf)
        acc[mf][nf] = __builtin_amdgcn_mfma_f32_16x16x32_bf16(af0[mf], bfr0[nf], acc[mf][nf], 0, 0, 0);
    __builtin_amdgcn_s_setprio(0);

#pragma unroll
    for (int mf = 0; mf < 4; ++mf)
      afp0[mf] = *(const bf16x8*)(myA + (64 + mf * 16 + l16) * 128 + kb0);
    if (sA_ok) stage_half(stA + 16384, gA + 128 * lda + (long)(t + 1) * 128, lda, tid);
    LGKM4();
    __builtin_amdgcn_s_setprio(1);
#pragma unroll
    for (int mf = 0; mf < 4; ++mf)
#pragma unroll
      for (int nf = 0; nf < 4; ++nf)
        acc[mf][nf] = __builtin_amdgcn_mfma_f32_16x16x32_bf16(af1[mf], bfr1[nf], acc[mf][nf], 0, 0, 0);
    __builtin_amdgcn_s_setprio(0);
    BAR();

#pragma unroll
    for (int mf = 0; mf < 4; ++mf)
      afp1[mf] = *(const bf16x8*)(myA + (64 + mf * 16 + l16) * 128 + kb1);
    if (sB_ok) stage_half(stB, gB + (long)(t + 2) * 128, ldb, tid);
    LGKM4();
    __builtin_amdgcn_s_setprio(1);
#pragma unroll
    for (int mf = 0; mf < 4; ++mf)
#pragma unroll
      for (int nf = 0; nf < 4; ++nf)
        acc[4 + mf][nf] = __builtin_amdgcn_mfma_f32_16x16x32_bf16(afp0[mf], bfr0[nf], acc[4 + mf][nf], 0, 0, 0);
    __builtin_amdgcn_s_setprio(0);
    if (sA_ok) {
      if (sB_ok) { VMCNT2(); } else { VMCNT0(); }
      BAR();
    }

    if (sA_ok) {
#pragma unroll
      for (int nf = 0; nf < 4; ++nf)
        bfr0[nf] = *(const bf16x8*)(nB + (rB + nf * 16 + l16) * 128 + kb0);
#pragma unroll
      for (int mf = 0; mf < 4; ++mf)
        af0[mf] = *(const bf16x8*)(nA + (mf * 16 + l16) * 128 + kb0);
    }
    if (sB_ok) stage_half(stB + 16384, gB + 128 * ldb + (long)(t + 2) * 128, ldb, tid);
    if (sA_ok) { LGKM8(); } else { LGKM0(); }
    __builtin_amdgcn_s_setprio(1);
#pragma unroll
    for (int mf = 0; mf < 4; ++mf)
#pragma unroll
      for (int nf = 0; nf < 4; ++nf)
        acc[4 + mf][nf] = __builtin_amdgcn_mfma_f32_16x16x32_bf16(afp1[mf], bfr1[nf], acc[4 + mf][nf], 0, 0, 0);
    __builtin_amdgcn_s_setprio(0);
    BAR();
  }

#pragma unroll
  for (int mi = 0; mi < 8; ++mi) {
#pragma unroll
    for (int ni = 0; ni < 4; ++ni) {
      const int row = row0 + wm * 128 + mi * 16 + lq * 4;
      const int col = col0 + wn * 64 + ni * 16 + l16;
      f32x4 v = acc[mi][ni];
      if constexpr (EPI == EPI_HID) {
        float bias = a0[col];
        u16* dst = (col < 1024) ? (o0 + (size_t)col * 16384 + row)
                                : (o1 + (size_t)(col - 1024) * 16384 + row);
        *(ushort4*)dst = make_ushort4(f2b(v.x + bias), f2b(v.y + bias), f2b(v.z + bias), f2b(v.w + bias));
      }
    }
  }
}

// ---------- fused ATTN+PV ----------
// out1[bat][q][h] = (sum_j relu2(scale*(q.k)) * v[j][h]) * gate
// block: 256q x 256h, j-step 64; grid (64, 4); 512 thr, 1 block/CU.
// LDS: kbuf 2x16K @0/16K; vbuf 2x32K @32K/64K; P 32K @96K. Q in registers.
__device__ __forceinline__ void stage_k64(char* s, const char* g, int tid) {
#pragma unroll
  for (int i = 0; i < 2; ++i) {
    int o = (i * 512 + tid) * 16;
    int row = o >> 8;                      // 256B rows (d=128 bf16)
    int cb = o & 255;
    int scb = cb ^ ((row & 7) << 4);
    __builtin_amdgcn_global_load_lds((const __attribute__((address_space(1))) void*)(g + (long)row * 256 + scb),
                                     (__attribute__((address_space(3))) void*)(s + o), 16, 0, 0);
  }
}
__device__ __forceinline__ void stage_v256(char* s, const char* g, int tid) {
#pragma unroll
  for (int i = 0; i < 4; ++i) {
    int o = (i * 512 + tid) * 16;
    int row = o >> 7;                      // 128B rows (64 j bf16), 256 rows
    int cb = o & 127;
    int scb = cb ^ ((row & 7) << 4);
    __builtin_amdgcn_global_load_lds((const __attribute__((address_space(1))) void*)(g + (long)row * 32768 + scb),
                                     (__attribute__((address_space(3))) void*)(s + o), 16, 0, 0);
  }
}

__global__ __launch_bounds__(512, 2) void attnpv(
    const char* qb, const char* kb, const char* vt,
    const u16* gt, u16* out1) {
  extern __shared__ __align__(16) char lds[];
  const int tid = threadIdx.x;
  const int lane = tid & 63;
  const int wave = tid >> 6;
  const int wq = wave >> 2, wh = wave & 3;   // PV tiling: 2q x 4h
  const int l16 = lane & 15, lq = lane >> 4;
  const int bat = blockIdx.y;

  const int nwg = gridDim.x;                 // 64 (%8==0)
  const int qq = nwg >> 3;
  const int fid = blockIdx.x;
  const int swz = (fid & 7) * qq + (fid >> 3);
  const int qt = swz >> 2;                   // 16 q-tiles
  const int ht = swz & 3;                    // 4 h-tiles
  const int q0 = qt * 256, h0 = ht * 256;

  char* kbuf0 = lds;
  char* kbuf1 = lds + 16384;
  char* vbuf0 = lds + 32768;
  char* vbuf1 = lds + 65536;
  char* pbuf = lds + 98304;

  const char* kb_g = kb + ((size_t)bat * 4096) * 256;
  const char* vt_g = vt + (size_t)h0 * 32768 + ((size_t)bat * 4096) * 2;

  const int kmask = (l16 & 7) << 4;

  // Q fragments (wave's 32 q-rows, full d=128). PLAIN offsets — the LDS K-read
  // XOR cancels its store-side swizzle, so K frags hold unpermuted d-slices;
  // Q (direct global->reg) must match with the unpermuted map. (r8 bugfix)
  bf16x8 qf[2][4];
  {
    const char* qg = qb + ((size_t)(bat * 4096 + q0 + wave * 32)) * 256;
#pragma unroll
    for (int mf = 0; mf < 2; ++mf)
#pragma unroll
      for (int kk = 0; kk < 4; ++kk)
        qf[mf][kk] = *(const bf16x8*)(qg + (size_t)(mf * 16 + l16) * 256 + (kk * 64 + lq * 16));
  }

  f32x4 acc[8][4];
#pragma unroll
  for (int i = 0; i < 8; ++i)
#pragma unroll
    for (int j = 0; j < 4; ++j) acc[i][j] = (f32x4){0.f, 0.f, 0.f, 0.f};

  // prologue: stage j-tile 0
  stage_k64(kbuf0, kb_g, tid);
  stage_v256(vbuf0, vt_g, tid);
  VMCNT0();
  BAR();

  const float scale = 0.088388347648318447f;  // 128^-0.5

  for (int jt = 0; jt < 64; ++jt) {
    char* kc = (jt & 1) ? kbuf1 : kbuf0;
    char* vc = (jt & 1) ? vbuf1 : vbuf0;
    char* kn = (jt & 1) ? kbuf0 : kbuf1;
    char* vn = (jt & 1) ? vbuf0 : vbuf1;
    // stage next j-tile (lands during this step; waited at VMCNT0 below)
    if (jt + 1 < 64) {
      stage_k64(kn, kb_g + (size_t)(jt + 1) * 16384, tid);
      stage_v256(vn, vt_g + (size_t)(jt + 1) * 128, tid);
    }

    // ---- S phase: s = Q . K^T  (wave: 32q x 64j, K from LDS)
    f32x4 sacc[2][4];
#pragma unroll
    for (int i = 0; i < 2; ++i)
#pragma unroll
      for (int j = 0; j < 4; ++j) sacc[i][j] = (f32x4){0.f, 0.f, 0.f, 0.f};
#pragma unroll
    for (int kh = 0; kh < 2; ++kh) {
      bf16x8 kfr[8];
#pragma unroll
      for (int nf = 0; nf < 4; ++nf)
#pragma unroll
        for (int ki = 0; ki < 2; ++ki)
          kfr[nf * 2 + ki] = *(const bf16x8*)(kc + (nf * 16 + l16) * 256 + (((kh * 2 + ki) * 64 + lq * 16) ^ kmask));
      __builtin_amdgcn_s_setprio(1);
#pragma unroll
      for (int ki = 0; ki < 2; ++ki)
#pragma unroll
        for (int mf = 0; mf < 2; ++mf)
#pragma unroll
          for (int nf = 0; nf < 4; ++nf)
            sacc[mf][nf] = __builtin_amdgcn_mfma_f32_16x16x32_bf16(qf[mf][kh * 2 + ki], kfr[nf * 2 + ki], sacc[mf][nf], 0, 0, 0);
      __builtin_amdgcn_s_setprio(0);
    }

    // ---- P epilogue: relu^2(scale*s) -> bf16 -> swizzled LDS [256q][64j]
#pragma unroll
    for (int mf = 0; mf < 2; ++mf)
#pragma unroll
      for (int nf = 0; nf < 4; ++nf)
#pragma unroll
        for (int i = 0; i < 4; ++i) {
          int qloc = wave * 32 + mf * 16 + lq * 4 + i;
          float t = sacc[mf][nf][i] * scale;
          t = t > 0.f ? t * t : 0.f;
          int byte = qloc * 128 + (((nf * 16 + l16) * 2) ^ ((qloc & 7) << 4));
          *(u16*)(pbuf + byte) = f2b(t);
        }
    LGKM0();
    BAR();  // P visible to all waves

    // ---- PV phase: acc += P . V^T  (wave: 128q x 64h)
#pragma unroll
    for (int ki = 0; ki < 2; ++ki) {
      bf16x8 pa[8], vf[4];
#pragma unroll
      for (int mf = 0; mf < 8; ++mf)
        pa[mf] = *(const bf16x8*)(pbuf + (wq * 128 + mf * 16 + l16) * 128 + ((ki * 64 + lq * 16) ^ kmask));
#pragma unroll
      for (int nf = 0; nf < 4; ++nf)
        vf[nf] = *(const bf16x8*)(vc + (wh * 64 + nf * 16 + l16) * 128 + ((ki * 64 + lq * 16) ^ kmask));
      __builtin_amdgcn_s_setprio(1);
#pragma unroll
      for (int mf = 0; mf < 8; ++mf)
#pragma unroll
        for (int nf = 0; nf < 4; ++nf)
          acc[mf][nf] = __builtin_amdgcn_mfma_f32_16x16x32_bf16(pa[mf], vf[nf], acc[mf][nf], 0, 0, 0);
      __builtin_amdgcn_s_setprio(0);
    }
    VMCNT0();  // next K/V landed (issued a full step ago -> no stall)
    BAR();     // P-reads done (next S may overwrite); staged tiles visible
  }

  // ---- epilogue: * gate, store bf16 out1
#pragma unroll
  for (int mi = 0; mi < 8; ++mi) {
#pragma unroll
    for (int ni = 0; ni < 4; ++ni) {
      const int row = q0 + wq * 128 + mi * 16 + lq * 4;
      const int col = h0 + wh * 64 + ni * 16 + l16;
      f32x4 v = acc[mi][ni];
      const u16* gp = gt + (size_t)col * 16384 + (size_t)bat * 4096 + row;
      ushort4 g = *(const ushort4*)gp;
      u16* dst = out1 + (size_t)bat * 4096 * 1024;
      dst[(size_t)(row + 0) * 1024 + col] = f2b(v.x * b2f(g.x));
      dst[(size_t)(row + 1) * 1024 + col] = f2b(v.y * b2f(g.y));
      dst[(size_t)(row + 2) * 1024 + col] = f2b(v.z * b2f(g.z));
      dst[(size_t)(row + 3) * 1024 + col] = f2b(v.w * b2f(g.w));
    }
  }
}

__global__ void conv_b(const float* in, u16* out, int n) {
  int i = (blockIdx.x * blockDim.x + threadIdx.x) * 4;
  if (i >= n) return;
  float4 f = *(const float4*)(in + i);
  *(ushort4*)(out + i) = make_ushort4(f2b(f.x), f2b(f.y), f2b(f.z), f2b(f.w));
}

__global__ void transpose_b(const float* in, u16* out, int R, int C) {
  int o = blockIdx.x * blockDim.x + threadIdx.x;
  if (o >= R * C) return;
  int c = o / R, r = o - c * R;
  out[o] = f2b(in[(size_t)r * C + c]);
}

extern "C" void kernel_launch(void* const* d_in, const int* in_sizes, int n_in,
                              void* d_out, int out_size, void* d_ws, size_t ws_size,
                              hipStream_t stream) {
  const float* x = (const float*)d_in[0];
  const float* w_hidden = (const float*)d_in[1];
  const float* b_hidden = (const float*)d_in[2];
  const float* w_qk = (const float*)d_in[3];
  const float* q_gamma = (const float*)d_in[4];
  const float* q_beta = (const float*)d_in[5];
  const float* k_gamma = (const float*)d_in[6];
  const float* k_beta = (const float*)d_in[7];
  const float* w_out = (const float*)d_in[8];
  const float* b_out = (const float*)d_in[9];
  float* out = (float*)d_out;

  char* ws = (char*)d_ws;
  size_t off = 0;
  auto alloc = [&](size_t bytes) { char* p = ws + off; off += (bytes + 255) & ~255ull; return p; };
  u16* xb     = (u16*)alloc(16384ull * 512 * 2);
  u16* wh_t   = (u16*)alloc(2048ull * 512 * 2);
  u16* wqk_t  = (u16*)alloc(128ull * 512 * 2);
  u16* wout_t = (u16*)alloc(512ull * 1024 * 2);
  u16* v_t    = (u16*)alloc(1024ull * 16384 * 2);
  u16* g_t    = (u16*)alloc(1024ull * 16384 * 2);
  u16* qb_a   = (u16*)alloc(16384ull * 128 * 2);
  u16* kb_a   = (u16*)alloc(16384ull * 128 * 2);
  u16* out1b  = (u16*)alloc(16384ull * 1024 * 2);

  (void)hipFuncSetAttribute((const void*)gemm256<EPI_HID>, hipFuncAttributeMaxDynamicSharedMemorySize, 131072);
  (void)hipFuncSetAttribute((const void*)attnpv, hipFuncAttributeMaxDynamicSharedMemorySize, 131072);

  conv_b<<<(16384 * 512 / 4 + 255) / 256, 256, 0, stream>>>(x, xb, 16384 * 512);
  transpose_b<<<(512 * 2048 + 255) / 256, 256, 0, stream>>>(w_hidden, wh_t, 512, 2048);
  transpose_b<<<(512 * 128 + 255) / 256, 256, 0, stream>>>(w_qk, wqk_t, 512, 128);
  transpose_b<<<(1024 * 512 + 255) / 256, 256, 0, stream>>>(w_out, wout_t, 1024, 512);

  // GEMM1: hid = x @ Wh (+bias) -> v_t, g_t (transposed bf16). M=16384 N=2048 K=512
  gemm256<EPI_HID><<<dim3(512, 1), 512, 131072, stream>>>(
      (const char*)xb, (const char*)wh_t, 0, 0, 1024, 1024, 8, 8,
      v_t, g_t, b_hidden, nullptr, nullptr);
  // GEMM2: qk = x @ Wqk -> q,k (offset-scale). N=128
  gemm_tn<EPI_QK><<<dim3(1, 128, 1), 256, 0, stream>>>(
      (const char*)xb, (const char*)wqk_t, 0, 0, 1024, 1024, 8,
      qb_a, kb_a, q_gamma, q_beta, k_gamma, k_beta, nullptr, nullptr);
  // fused: out1 = (relu2(scale*q k^T) @ v) * gate
  attnpv<<<dim3(64, 4), 512, 131072, stream>>>(
      (const char*)qb_a, (const char*)kb_a, (const char*)v_t, g_t, out1b);
  // out = out1 @ Wout + b_out + x. M=16384 N=512 K=1024
  gemm_tn<EPI_OUT><<<dim3(4, 128, 1), 256, 0, stream>>>(
      (const char*)out1b, (const char*)wout_t, 0, 0, 2048, 2048, 16,
      nullptr, nullptr, b_out, nullptr, nullptr, nullptr, out, x);
}

// Round 10
// 327.097 us; speedup vs baseline: 1.4375x; 1.4375x over previous
//
#include <hip/hip_runtime.h>
#include <hip/hip_bf16.h>

typedef __attribute__((ext_vector_type(8))) short bf16x8;
typedef __attribute__((ext_vector_type(4))) float f32x4;
typedef unsigned short u16;

__device__ __forceinline__ u16 f2b(float f) {
  __hip_bfloat16 h = __float2bfloat16(f);
  return __builtin_bit_cast(unsigned short, h);
}
__device__ __forceinline__ float b2f(u16 u) {
  __hip_bfloat16 h = __builtin_bit_cast(__hip_bfloat16, u);
  return __bfloat162float(h);
}

#define BAR() __builtin_amdgcn_s_barrier()
#define LGKM0() do { asm volatile("s_waitcnt lgkmcnt(0)" ::: "memory"); __builtin_amdgcn_sched_barrier(0); } while (0)
#define LGKM4() do { asm volatile("s_waitcnt lgkmcnt(4)" ::: "memory"); __builtin_amdgcn_sched_barrier(0); } while (0)
#define LGKM8() do { asm volatile("s_waitcnt lgkmcnt(8)" ::: "memory"); __builtin_amdgcn_sched_barrier(0); } while (0)
#define VMCNT4() asm volatile("s_waitcnt vmcnt(4)" ::: "memory")
#define VMCNT2() asm volatile("s_waitcnt vmcnt(2)" ::: "memory")
#define VMCNT0() asm volatile("s_waitcnt vmcnt(0)" ::: "memory")

#define EPI_HID 0
#define EPI_QK 1
#define EPI_ATTN 2
#define EPI_PV 3
#define EPI_OUT 4

// ---------- 128^2 2-phase kernel (QK: N=128; OUT: N=512) ----------
__device__ __forceinline__ void stage_tile(char* sbase, const char* gbase, int ld_bytes, int tid) {
#pragma unroll
  for (int i = 0; i < 4; ++i) {
    int o = (i * 256 + tid) * 16;
    int row = o >> 7;
    int cb = o & 127;
    int scb = cb ^ ((row & 7) << 4);
    const char* src = gbase + (long)row * ld_bytes + scb;
    __builtin_amdgcn_global_load_lds((const __attribute__((address_space(1))) void*)src,
                                     (__attribute__((address_space(3))) void*)(sbase + o),
                                     16, 0, 0);
  }
}

template <int EPI>
__global__ __launch_bounds__(256, 2) void gemm_tn(
    const char* Ab, const char* Bb, long sAbat, long sBbat,
    int lda_b, int ldb_b, int nkt,
    u16* o0, u16* o1,
    const float* a0, const float* a1, const float* a2, const float* a3,
    float* fout, const float* xres) {
  __shared__ __align__(16) char lds[32768];
  char* sA = lds;
  char* sB = lds + 16384;
  const int tid = threadIdx.x;
  const int lane = tid & 63;
  const int wave = tid >> 6;
  const int wm = wave >> 1, wn = wave & 1;
  const int l16 = lane & 15, lq = lane >> 4;
  const int bat = blockIdx.z;
  const int row0 = blockIdx.y * 128;
  const int col0 = blockIdx.x * 128;

  const char* Abase = Ab + (long)bat * sAbat + (long)row0 * lda_b;
  const char* Bbase = Bb + (long)bat * sBbat + (long)col0 * ldb_b;

  f32x4 acc[4][4];
#pragma unroll
  for (int i = 0; i < 4; ++i)
#pragma unroll
    for (int j = 0; j < 4; ++j) acc[i][j] = (f32x4){0.f, 0.f, 0.f, 0.f};

  for (int kt = 0; kt < nkt; ++kt) {
    stage_tile(sA, Abase + (long)kt * 128, lda_b, tid);
    stage_tile(sB, Bbase + (long)kt * 128, ldb_b, tid);
    __syncthreads();
#pragma unroll
    for (int kk = 0; kk < 2; ++kk) {
      bf16x8 af[4], bfr[4];
#pragma unroll
      for (int mf = 0; mf < 4; ++mf) {
        int r = wm * 64 + mf * 16 + l16;
        int kb = kk * 64 + lq * 16;
        af[mf] = *(const bf16x8*)(sA + r * 128 + (kb ^ ((r & 7) << 4)));
      }
#pragma unroll
      for (int nf = 0; nf < 4; ++nf) {
        int r = wn * 64 + nf * 16 + l16;
        int kb = kk * 64 + lq * 16;
        bfr[nf] = *(const bf16x8*)(sB + r * 128 + (kb ^ ((r & 7) << 4)));
      }
#pragma unroll
      for (int mf = 0; mf < 4; ++mf)
#pragma unroll
        for (int nf = 0; nf < 4; ++nf)
          acc[mf][nf] = __builtin_amdgcn_mfma_f32_16x16x32_bf16(af[mf], bfr[nf], acc[mf][nf], 0, 0, 0);
    }
    __syncthreads();
  }

#pragma unroll
  for (int mf = 0; mf < 4; ++mf) {
#pragma unroll
    for (int nf = 0; nf < 4; ++nf) {
      const int row = row0 + wm * 64 + mf * 16 + lq * 4;
      const int col = col0 + wn * 64 + nf * 16 + l16;
      f32x4 v = acc[mf][nf];
      if constexpr (EPI == EPI_QK) {
        float qg = a0[col], qbt = a1[col], kg = a2[col], kbt = a3[col];
#pragma unroll
        for (int i = 0; i < 4; ++i) {
          float t = v[i];
          o0[(size_t)(row + i) * 128 + col] = f2b(t * qg + qbt);
          o1[(size_t)(row + i) * 128 + col] = f2b(t * kg + kbt);
        }
      } else if constexpr (EPI == EPI_OUT) {
        float bias = a0[col];
#pragma unroll
        for (int i = 0; i < 4; ++i)
          fout[(size_t)(row + i) * 512 + col] = v[i] + bias + xres[(size_t)(row + i) * 512 + col];
      }
    }
  }
}

// ---------- 256^2 16x16 minimal-barrier kernel (HID, ATTN, PV) ----------
// 512 threads = 8 waves (2m x 4n); BK=64; LDS 128KiB = 2 bufs x (A 32K + B 32K).
// 3 barriers per K-tile; counted lgkm waits; reads issued one phase ahead.
__device__ __forceinline__ void stage_half(char* sbase, const char* gbase, long ld, int tid) {
#pragma unroll
  for (int i = 0; i < 2; ++i) {
    int o = (i * 512 + tid) * 16;
    int row = o >> 7;
    int cb = o & 127;
    int scb = cb ^ ((row & 7) << 4);
    const char* src = gbase + (long)row * ld + scb;
    __builtin_amdgcn_global_load_lds((const __attribute__((address_space(1))) void*)src,
                                     (__attribute__((address_space(3))) void*)(sbase + o),
                                     16, 0, 0);
  }
}

template <int EPI>
__global__ __launch_bounds__(512, 2) void gemm256(
    const char* Ab, const char* Bb, long sAbat, long sBbat,
    long lda, long ldb, int nkt, int nx,
    u16* o0, u16* o1,
    const float* a0, float* fout, const float* xres) {
  extern __shared__ __align__(16) char lds[];
  const int tid = threadIdx.x;
  const int lane = tid & 63;
  const int wave = tid >> 6;
  const int wm = wave >> 2;
  const int wn = wave & 3;
  const int l16 = lane & 15, lq = lane >> 4;
  const int bat = blockIdx.y;

  const int nwg = gridDim.x;
  const int qq = nwg >> 3;
  const int fid = blockIdx.x;
  const int swz = (fid & 7) * qq + (fid >> 3);
  const int row0 = (swz / nx) * 256;
  const int col0 = (swz % nx) * 256;

  const char* gA = Ab + (long)bat * sAbat + (long)row0 * lda;
  const char* gB = Bb + (long)bat * sBbat + (long)col0 * ldb;

  f32x4 acc[8][4];
#pragma unroll
  for (int i = 0; i < 8; ++i)
#pragma unroll
    for (int j = 0; j < 4; ++j) acc[i][j] = (f32x4){0.f, 0.f, 0.f, 0.f};

  const int kmask = (l16 & 7) << 4;
  const int kb0 = (lq * 16) ^ kmask;
  const int kb1 = (64 + lq * 16) ^ kmask;
  const int rB = (wn & 1) * 64;

  stage_half(lds + 32768, gB, ldb, tid);
  stage_half(lds + 32768 + 16384, gB + 128 * ldb, ldb, tid);
  stage_half(lds, gA, lda, tid);
  stage_half(lds + 16384, gA + 128 * lda, lda, tid);
  if (nkt > 1) {
    stage_half(lds + 65536 + 32768, gB + 128, ldb, tid);
    stage_half(lds + 65536 + 32768 + 16384, gB + 128 * ldb + 128, ldb, tid);
    VMCNT4();
  } else {
    VMCNT0();
  }
  BAR();

  bf16x8 af0[4], af1[4], afp0[4], afp1[4], bfr0[4], bfr1[4];
  {
    const char* myA = lds + wm * 16384;
    const char* myB = lds + 32768 + (wn >> 1) * 16384;
#pragma unroll
    for (int nf = 0; nf < 4; ++nf)
      bfr0[nf] = *(const bf16x8*)(myB + (rB + nf * 16 + l16) * 128 + kb0);
#pragma unroll
    for (int mf = 0; mf < 4; ++mf)
      af0[mf] = *(const bf16x8*)(myA + (mf * 16 + l16) * 128 + kb0);
  }

  for (int t = 0; t < nkt; ++t) {
    const char* bufc = lds + (t & 1) * 65536;
    const char* bufn = lds + ((t + 1) & 1) * 65536;
    const char* myA = bufc + wm * 16384;
    const char* myB = bufc + 32768 + (wn >> 1) * 16384;
    const char* nA = bufn + wm * 16384;
    const char* nB = bufn + 32768 + (wn >> 1) * 16384;
    char* stA = (char*)bufn;
    char* stB = (char*)bufc + 32768;
    const bool sA_ok = (t + 1) < nkt;
    const bool sB_ok = (t + 2) < nkt;

#pragma unroll
    for (int nf = 0; nf < 4; ++nf)
      bfr1[nf] = *(const bf16x8*)(myB + (rB + nf * 16 + l16) * 128 + kb1);
#pragma unroll
    for (int mf = 0; mf < 4; ++mf)
      af1[mf] = *(const bf16x8*)(myA + (mf * 16 + l16) * 128 + kb1);
    if (sA_ok) stage_half(stA, gA + (long)(t + 1) * 128, lda, tid);
    LGKM8();
    __builtin_amdgcn_s_setprio(1);
#pragma unroll
    for (int mf = 0; mf < 4; ++mf)
#pragma unroll
      for (int nf = 0; nf < 4; ++nf)
        acc[mf][nf] = __builtin_amdgcn_mfma_f32_16x16x32_bf16(af0[mf], bfr0[nf], acc[mf][nf], 0, 0, 0);
    __builtin_amdgcn_s_setprio(0);

#pragma unroll
    for (int mf = 0; mf < 4; ++mf)
      afp0[mf] = *(const bf16x8*)(myA + (64 + mf * 16 + l16) * 128 + kb0);
    if (sA_ok) stage_half(stA + 16384, gA + 128 * lda + (long)(t + 1) * 128, lda, tid);
    LGKM4();
    __builtin_amdgcn_s_setprio(1);
#pragma unroll
    for (int mf = 0; mf < 4; ++mf)
#pragma unroll
      for (int nf = 0; nf < 4; ++nf)
        acc[mf][nf] = __builtin_amdgcn_mfma_f32_16x16x32_bf16(af1[mf], bfr1[nf], acc[mf][nf], 0, 0, 0);
    __builtin_amdgcn_s_setprio(0);
    BAR();

#pragma unroll
    for (int mf = 0; mf < 4; ++mf)
      afp1[mf] = *(const bf16x8*)(myA + (64 + mf * 16 + l16) * 128 + kb1);
    if (sB_ok) stage_half(stB, gB + (long)(t + 2) * 128, ldb, tid);
    LGKM4();
    __builtin_amdgcn_s_setprio(1);
#pragma unroll
    for (int mf = 0; mf < 4; ++mf)
#pragma unroll
      for (int nf = 0; nf < 4; ++nf)
        acc[4 + mf][nf] = __builtin_amdgcn_mfma_f32_16x16x32_bf16(afp0[mf], bfr0[nf], acc[4 + mf][nf], 0, 0, 0);
    __builtin_amdgcn_s_setprio(0);
    if (sA_ok) {
      if (sB_ok) { VMCNT2(); } else { VMCNT0(); }
      BAR();
    }

    if (sA_ok) {
#pragma unroll
      for (int nf = 0; nf < 4; ++nf)
        bfr0[nf] = *(const bf16x8*)(nB + (rB + nf * 16 + l16) * 128 + kb0);
#pragma unroll
      for (int mf = 0; mf < 4; ++mf)
        af0[mf] = *(const bf16x8*)(nA + (mf * 16 + l16) * 128 + kb0);
    }
    if (sB_ok) stage_half(stB + 16384, gB + 128 * ldb + (long)(t + 2) * 128, ldb, tid);
    if (sA_ok) { LGKM8(); } else { LGKM0(); }
    __builtin_amdgcn_s_setprio(1);
#pragma unroll
    for (int mf = 0; mf < 4; ++mf)
#pragma unroll
      for (int nf = 0; nf < 4; ++nf)
        acc[4 + mf][nf] = __builtin_amdgcn_mfma_f32_16x16x32_bf16(afp1[mf], bfr1[nf], acc[4 + mf][nf], 0, 0, 0);
    __builtin_amdgcn_s_setprio(0);
    BAR();
  }

  // epilogue
#pragma unroll
  for (int mi = 0; mi < 8; ++mi) {
#pragma unroll
    for (int ni = 0; ni < 4; ++ni) {
      const int row = row0 + wm * 128 + mi * 16 + lq * 4;
      const int col = col0 + wn * 64 + ni * 16 + l16;
      f32x4 v = acc[mi][ni];
      if constexpr (EPI == EPI_HID) {
        float bias = a0[col];
        u16* dst = (col < 1024) ? (o0 + (size_t)col * 16384 + row)
                                : (o1 + (size_t)(col - 1024) * 16384 + row);
        *(ushort4*)dst = make_ushort4(f2b(v.x + bias), f2b(v.y + bias), f2b(v.z + bias), f2b(v.w + bias));
      } else if constexpr (EPI == EPI_ATTN) {
        // swapped operands: C[j][q] = K . Q^T, so row=j (4 consecutive), col=q.
        // store attn[q][j..j+3] as one ushort4 (row-major attn, coalesced-ish).
        const float scale = 0.088388347648318447f;  // 128^-0.5
        u16* dst = o0 + (size_t)bat * 4096 * 4096;
        float t0 = v.x * scale; t0 = t0 > 0.f ? t0 * t0 : 0.f;
        float t1 = v.y * scale; t1 = t1 > 0.f ? t1 * t1 : 0.f;
        float t2 = v.z * scale; t2 = t2 > 0.f ? t2 * t2 : 0.f;
        float t3 = v.w * scale; t3 = t3 > 0.f ? t3 * t3 : 0.f;
        *(ushort4*)(dst + (size_t)col * 4096 + row) =
            make_ushort4(f2b(t0), f2b(t1), f2b(t2), f2b(t3));
      } else if constexpr (EPI == EPI_PV) {
        const u16* gt = o1 + (size_t)col * 16384 + (size_t)bat * 4096 + row;
        ushort4 g = *(const ushort4*)gt;
        u16* dst = o0 + (size_t)bat * 4096 * 1024;
        dst[(size_t)(row + 0) * 1024 + col] = f2b(v.x * b2f(g.x));
        dst[(size_t)(row + 1) * 1024 + col] = f2b(v.y * b2f(g.y));
        dst[(size_t)(row + 2) * 1024 + col] = f2b(v.z * b2f(g.z));
        dst[(size_t)(row + 3) * 1024 + col] = f2b(v.w * b2f(g.w));
      }
    }
  }
}

__global__ void conv_b(const float* in, u16* out, int n) {
  int i = (blockIdx.x * blockDim.x + threadIdx.x) * 4;
  if (i >= n) return;
  float4 f = *(const float4*)(in + i);
  *(ushort4*)(out + i) = make_ushort4(f2b(f.x), f2b(f.y), f2b(f.z), f2b(f.w));
}

__global__ void transpose_b(const float* in, u16* out, int R, int C) {
  int o = blockIdx.x * blockDim.x + threadIdx.x;
  if (o >= R * C) return;
  int c = o / R, r = o - c * R;
  out[o] = f2b(in[(size_t)r * C + c]);
}

extern "C" void kernel_launch(void* const* d_in, const int* in_sizes, int n_in,
                              void* d_out, int out_size, void* d_ws, size_t ws_size,
                              hipStream_t stream) {
  const float* x = (const float*)d_in[0];
  const float* w_hidden = (const float*)d_in[1];
  const float* b_hidden = (const float*)d_in[2];
  const float* w_qk = (const float*)d_in[3];
  const float* q_gamma = (const float*)d_in[4];
  const float* q_beta = (const float*)d_in[5];
  const float* k_gamma = (const float*)d_in[6];
  const float* k_beta = (const float*)d_in[7];
  const float* w_out = (const float*)d_in[8];
  const float* b_out = (const float*)d_in[9];
  float* out = (float*)d_out;

  char* ws = (char*)d_ws;
  size_t off = 0;
  auto alloc = [&](size_t bytes) { char* p = ws + off; off += (bytes + 255) & ~255ull; return p; };
  u16* xb     = (u16*)alloc(16384ull * 512 * 2);
  u16* wh_t   = (u16*)alloc(2048ull * 512 * 2);
  u16* wqk_t  = (u16*)alloc(128ull * 512 * 2);
  u16* wout_t = (u16*)alloc(512ull * 1024 * 2);
  u16* v_t    = (u16*)alloc(1024ull * 16384 * 2);
  u16* g_t    = (u16*)alloc(1024ull * 16384 * 2);
  u16* qb_a   = (u16*)alloc(16384ull * 128 * 2);
  u16* kb_a   = (u16*)alloc(16384ull * 128 * 2);
  u16* attnb  = (u16*)alloc(4ull * 4096 * 4096 * 2);
  u16* out1b  = (u16*)alloc(16384ull * 1024 * 2);

  (void)hipFuncSetAttribute((const void*)gemm256<EPI_HID>, hipFuncAttributeMaxDynamicSharedMemorySize, 131072);
  (void)hipFuncSetAttribute((const void*)gemm256<EPI_ATTN>, hipFuncAttributeMaxDynamicSharedMemorySize, 131072);
  (void)hipFuncSetAttribute((const void*)gemm256<EPI_PV>, hipFuncAttributeMaxDynamicSharedMemorySize, 131072);

  conv_b<<<(16384 * 512 / 4 + 255) / 256, 256, 0, stream>>>(x, xb, 16384 * 512);
  transpose_b<<<(512 * 2048 + 255) / 256, 256, 0, stream>>>(w_hidden, wh_t, 512, 2048);
  transpose_b<<<(512 * 128 + 255) / 256, 256, 0, stream>>>(w_qk, wqk_t, 512, 128);
  transpose_b<<<(1024 * 512 + 255) / 256, 256, 0, stream>>>(w_out, wout_t, 1024, 512);

  // GEMM1: hid = x @ Wh (+bias) -> v_t, g_t (transposed bf16). M=16384 N=2048 K=512
  gemm256<EPI_HID><<<dim3(512, 1), 512, 131072, stream>>>(
      (const char*)xb, (const char*)wh_t, 0, 0, 1024, 1024, 8, 8,
      v_t, g_t, b_hidden, nullptr, nullptr);
  // GEMM2: qk = x @ Wqk -> q,k (offset-scale). N=128
  gemm_tn<EPI_QK><<<dim3(1, 128, 1), 256, 0, stream>>>(
      (const char*)xb, (const char*)wqk_t, 0, 0, 1024, 1024, 8,
      qb_a, kb_a, q_gamma, q_beta, k_gamma, k_beta, nullptr, nullptr);
  // sim: C[j][q] = K @ Q^T (swapped operands), relu^2(scale*) -> attn[q][j] bf16
  gemm256<EPI_ATTN><<<dim3(256, 4), 512, 131072, stream>>>(
      (const char*)kb_a, (const char*)qb_a, 4096ll * 256, 4096ll * 256, 256, 256, 2, 16,
      attnb, nullptr, nullptr, nullptr, nullptr);
  // out1 = (attn @ v) * gate. per batch M=4096 N=1024 K=4096
  gemm256<EPI_PV><<<dim3(64, 4), 512, 131072, stream>>>(
      (const char*)attnb, (const char*)v_t, 4096ll * 8192, 8192, 8192, 32768, 64, 4,
      out1b, g_t, nullptr, nullptr, nullptr);
  // out = out1 @ Wout + b_out + x. M=16384 N=512 K=1024
  gemm_tn<EPI_OUT><<<dim3(4, 128, 1), 256, 0, stream>>>(
      (const char*)out1b, (const char*)wout_t, 0, 0, 2048, 2048, 16,
      nullptr, nullptr, b_out, nullptr, nullptr, nullptr, out, x);
}

// Round 11
// 316.490 us; speedup vs baseline: 1.4857x; 1.0335x over previous
//
#include <hip/hip_runtime.h>
#include <hip/hip_bf16.h>

typedef __attribute__((ext_vector_type(8))) short bf16x8;
typedef __attribute__((ext_vector_type(4))) float f32x4;
typedef unsigned short u16;

__device__ __forceinline__ u16 f2b(float f) {
  __hip_bfloat16 h = __float2bfloat16(f);
  return __builtin_bit_cast(unsigned short, h);
}
__device__ __forceinline__ float b2f(u16 u) {
  __hip_bfloat16 h = __builtin_bit_cast(__hip_bfloat16, u);
  return __bfloat162float(h);
}

#define BAR() __builtin_amdgcn_s_barrier()
#define LGKM0() do { asm volatile("s_waitcnt lgkmcnt(0)" ::: "memory"); __builtin_amdgcn_sched_barrier(0); } while (0)
#define LGKM4() do { asm volatile("s_waitcnt lgkmcnt(4)" ::: "memory"); __builtin_amdgcn_sched_barrier(0); } while (0)
#define LGKM8() do { asm volatile("s_waitcnt lgkmcnt(8)" ::: "memory"); __builtin_amdgcn_sched_barrier(0); } while (0)
#define VMCNT4() asm volatile("s_waitcnt vmcnt(4)" ::: "memory")
#define VMCNT2() asm volatile("s_waitcnt vmcnt(2)" ::: "memory")
#define VMCNT0() asm volatile("s_waitcnt vmcnt(0)" ::: "memory")

#define EPI_HID 0
#define EPI_QK 1
#define EPI_PV 3
#define EPI_OUT 4

// ---------- 128^2 2-phase kernel (QK: N=128; OUT: N=512) ----------
__device__ __forceinline__ void stage_tile(char* sbase, const char* gbase, int ld_bytes, int tid) {
#pragma unroll
  for (int i = 0; i < 4; ++i) {
    int o = (i * 256 + tid) * 16;
    int row = o >> 7;
    int cb = o & 127;
    int scb = cb ^ ((row & 7) << 4);
    const char* src = gbase + (long)row * ld_bytes + scb;
    __builtin_amdgcn_global_load_lds((const __attribute__((address_space(1))) void*)src,
                                     (__attribute__((address_space(3))) void*)(sbase + o),
                                     16, 0, 0);
  }
}

template <int EPI>
__global__ __launch_bounds__(256, 2) void gemm_tn(
    const char* Ab, const char* Bb, long sAbat, long sBbat,
    int lda_b, int ldb_b, int nkt,
    u16* o0, u16* o1,
    const float* a0, const float* a1, const float* a2, const float* a3,
    float* fout, const float* xres) {
  __shared__ __align__(16) char lds[32768];
  char* sA = lds;
  char* sB = lds + 16384;
  const int tid = threadIdx.x;
  const int lane = tid & 63;
  const int wave = tid >> 6;
  const int wm = wave >> 1, wn = wave & 1;
  const int l16 = lane & 15, lq = lane >> 4;
  const int bat = blockIdx.z;
  const int row0 = blockIdx.y * 128;
  const int col0 = blockIdx.x * 128;

  const char* Abase = Ab + (long)bat * sAbat + (long)row0 * lda_b;
  const char* Bbase = Bb + (long)bat * sBbat + (long)col0 * ldb_b;

  f32x4 acc[4][4];
#pragma unroll
  for (int i = 0; i < 4; ++i)
#pragma unroll
    for (int j = 0; j < 4; ++j) acc[i][j] = (f32x4){0.f, 0.f, 0.f, 0.f};

  for (int kt = 0; kt < nkt; ++kt) {
    stage_tile(sA, Abase + (long)kt * 128, lda_b, tid);
    stage_tile(sB, Bbase + (long)kt * 128, ldb_b, tid);
    __syncthreads();
#pragma unroll
    for (int kk = 0; kk < 2; ++kk) {
      bf16x8 af[4], bfr[4];
#pragma unroll
      for (int mf = 0; mf < 4; ++mf) {
        int r = wm * 64 + mf * 16 + l16;
        int kb = kk * 64 + lq * 16;
        af[mf] = *(const bf16x8*)(sA + r * 128 + (kb ^ ((r & 7) << 4)));
      }
#pragma unroll
      for (int nf = 0; nf < 4; ++nf) {
        int r = wn * 64 + nf * 16 + l16;
        int kb = kk * 64 + lq * 16;
        bfr[nf] = *(const bf16x8*)(sB + r * 128 + (kb ^ ((r & 7) << 4)));
      }
#pragma unroll
      for (int mf = 0; mf < 4; ++mf)
#pragma unroll
        for (int nf = 0; nf < 4; ++nf)
          acc[mf][nf] = __builtin_amdgcn_mfma_f32_16x16x32_bf16(af[mf], bfr[nf], acc[mf][nf], 0, 0, 0);
    }
    __syncthreads();
  }

#pragma unroll
  for (int mf = 0; mf < 4; ++mf) {
#pragma unroll
    for (int nf = 0; nf < 4; ++nf) {
      const int row = row0 + wm * 64 + mf * 16 + lq * 4;
      const int col = col0 + wn * 64 + nf * 16 + l16;
      f32x4 v = acc[mf][nf];
      if constexpr (EPI == EPI_QK) {
        float qg = a0[col], qbt = a1[col], kg = a2[col], kbt = a3[col];
#pragma unroll
        for (int i = 0; i < 4; ++i) {
          float t = v[i];
          o0[(size_t)(row + i) * 128 + col] = f2b(t * qg + qbt);
          o1[(size_t)(row + i) * 128 + col] = f2b(t * kg + kbt);
        }
      } else if constexpr (EPI == EPI_OUT) {
        float bias = a0[col];
#pragma unroll
        for (int i = 0; i < 4; ++i)
          fout[(size_t)(row + i) * 512 + col] = v[i] + bias + xres[(size_t)(row + i) * 512 + col];
      }
    }
  }
}

// ---------- 256^2 16x16 minimal-barrier kernel (HID, PV) — round-6 best ----------
__device__ __forceinline__ void stage_half(char* sbase, const char* gbase, long ld, int tid) {
#pragma unroll
  for (int i = 0; i < 2; ++i) {
    int o = (i * 512 + tid) * 16;
    int row = o >> 7;
    int cb = o & 127;
    int scb = cb ^ ((row & 7) << 4);
    const char* src = gbase + (long)row * ld + scb;
    __builtin_amdgcn_global_load_lds((const __attribute__((address_space(1))) void*)src,
                                     (__attribute__((address_space(3))) void*)(sbase + o),
                                     16, 0, 0);
  }
}

template <int EPI>
__global__ __launch_bounds__(512, 2) void gemm256(
    const char* Ab, const char* Bb, long sAbat, long sBbat,
    long lda, long ldb, int nkt, int nx,
    u16* o0, u16* o1,
    const float* a0, float* fout, const float* xres) {
  extern __shared__ __align__(16) char lds[];
  const int tid = threadIdx.x;
  const int lane = tid & 63;
  const int wave = tid >> 6;
  const int wm = wave >> 2;
  const int wn = wave & 3;
  const int l16 = lane & 15, lq = lane >> 4;
  const int bat = blockIdx.y;

  const int nwg = gridDim.x;
  const int qq = nwg >> 3;
  const int fid = blockIdx.x;
  const int swz = (fid & 7) * qq + (fid >> 3);
  const int row0 = (swz / nx) * 256;
  const int col0 = (swz % nx) * 256;

  const char* gA = Ab + (long)bat * sAbat + (long)row0 * lda;
  const char* gB = Bb + (long)bat * sBbat + (long)col0 * ldb;

  f32x4 acc[8][4];
#pragma unroll
  for (int i = 0; i < 8; ++i)
#pragma unroll
    for (int j = 0; j < 4; ++j) acc[i][j] = (f32x4){0.f, 0.f, 0.f, 0.f};

  const int kmask = (l16 & 7) << 4;
  const int kb0 = (lq * 16) ^ kmask;
  const int kb1 = (64 + lq * 16) ^ kmask;
  const int rB = (wn & 1) * 64;

  stage_half(lds + 32768, gB, ldb, tid);
  stage_half(lds + 32768 + 16384, gB + 128 * ldb, ldb, tid);
  stage_half(lds, gA, lda, tid);
  stage_half(lds + 16384, gA + 128 * lda, lda, tid);
  if (nkt > 1) {
    stage_half(lds + 65536 + 32768, gB + 128, ldb, tid);
    stage_half(lds + 65536 + 32768 + 16384, gB + 128 * ldb + 128, ldb, tid);
    VMCNT4();
  } else {
    VMCNT0();
  }
  BAR();

  bf16x8 af0[4], af1[4], afp0[4], afp1[4], bfr0[4], bfr1[4];
  {
    const char* myA = lds + wm * 16384;
    const char* myB = lds + 32768 + (wn >> 1) * 16384;
#pragma unroll
    for (int nf = 0; nf < 4; ++nf)
      bfr0[nf] = *(const bf16x8*)(myB + (rB + nf * 16 + l16) * 128 + kb0);
#pragma unroll
    for (int mf = 0; mf < 4; ++mf)
      af0[mf] = *(const bf16x8*)(myA + (mf * 16 + l16) * 128 + kb0);
  }

  for (int t = 0; t < nkt; ++t) {
    const char* bufc = lds + (t & 1) * 65536;
    const char* bufn = lds + ((t + 1) & 1) * 65536;
    const char* myA = bufc + wm * 16384;
    const char* myB = bufc + 32768 + (wn >> 1) * 16384;
    const char* nA = bufn + wm * 16384;
    const char* nB = bufn + 32768 + (wn >> 1) * 16384;
    char* stA = (char*)bufn;
    char* stB = (char*)bufc + 32768;
    const bool sA_ok = (t + 1) < nkt;
    const bool sB_ok = (t + 2) < nkt;

#pragma unroll
    for (int nf = 0; nf < 4; ++nf)
      bfr1[nf] = *(const bf16x8*)(myB + (rB + nf * 16 + l16) * 128 + kb1);
#pragma unroll
    for (int mf = 0; mf < 4; ++mf)
      af1[mf] = *(const bf16x8*)(myA + (mf * 16 + l16) * 128 + kb1);
    if (sA_ok) stage_half(stA, gA + (long)(t + 1) * 128, lda, tid);
    LGKM8();
    __builtin_amdgcn_s_setprio(1);
#pragma unroll
    for (int mf = 0; mf < 4; ++mf)
#pragma unroll
      for (int nf = 0; nf < 4; ++nf)
        acc[mf][nf] = __builtin_amdgcn_mfma_f32_16x16x32_bf16(af0[mf], bfr0[nf], acc[mf][nf], 0, 0, 0);
    __builtin_amdgcn_s_setprio(0);

#pragma unroll
    for (int mf = 0; mf < 4; ++mf)
      afp0[mf] = *(const bf16x8*)(myA + (64 + mf * 16 + l16) * 128 + kb0);
    if (sA_ok) stage_half(stA + 16384, gA + 128 * lda + (long)(t + 1) * 128, lda, tid);
    LGKM4();
    __builtin_amdgcn_s_setprio(1);
#pragma unroll
    for (int mf = 0; mf < 4; ++mf)
#pragma unroll
      for (int nf = 0; nf < 4; ++nf)
        acc[mf][nf] = __builtin_amdgcn_mfma_f32_16x16x32_bf16(af1[mf], bfr1[nf], acc[mf][nf], 0, 0, 0);
    __builtin_amdgcn_s_setprio(0);
    BAR();

#pragma unroll
    for (int mf = 0; mf < 4; ++mf)
      afp1[mf] = *(const bf16x8*)(myA + (64 + mf * 16 + l16) * 128 + kb1);
    if (sB_ok) stage_half(stB, gB + (long)(t + 2) * 128, ldb, tid);
    LGKM4();
    __builtin_amdgcn_s_setprio(1);
#pragma unroll
    for (int mf = 0; mf < 4; ++mf)
#pragma unroll
      for (int nf = 0; nf < 4; ++nf)
        acc[4 + mf][nf] = __builtin_amdgcn_mfma_f32_16x16x32_bf16(afp0[mf], bfr0[nf], acc[4 + mf][nf], 0, 0, 0);
    __builtin_amdgcn_s_setprio(0);
    if (sA_ok) {
      if (sB_ok) { VMCNT2(); } else { VMCNT0(); }
      BAR();
    }

    if (sA_ok) {
#pragma unroll
      for (int nf = 0; nf < 4; ++nf)
        bfr0[nf] = *(const bf16x8*)(nB + (rB + nf * 16 + l16) * 128 + kb0);
#pragma unroll
      for (int mf = 0; mf < 4; ++mf)
        af0[mf] = *(const bf16x8*)(nA + (mf * 16 + l16) * 128 + kb0);
    }
    if (sB_ok) stage_half(stB + 16384, gB + 128 * ldb + (long)(t + 2) * 128, ldb, tid);
    if (sA_ok) { LGKM8(); } else { LGKM0(); }
    __builtin_amdgcn_s_setprio(1);
#pragma unroll
    for (int mf = 0; mf < 4; ++mf)
#pragma unroll
      for (int nf = 0; nf < 4; ++nf)
        acc[4 + mf][nf] = __builtin_amdgcn_mfma_f32_16x16x32_bf16(afp1[mf], bfr1[nf], acc[4 + mf][nf], 0, 0, 0);
    __builtin_amdgcn_s_setprio(0);
    BAR();
  }

  // epilogue
#pragma unroll
  for (int mi = 0; mi < 8; ++mi) {
#pragma unroll
    for (int ni = 0; ni < 4; ++ni) {
      const int row = row0 + wm * 128 + mi * 16 + lq * 4;
      const int col = col0 + wn * 64 + ni * 16 + l16;
      f32x4 v = acc[mi][ni];
      if constexpr (EPI == EPI_HID) {
        float bias = a0[col];
        u16* dst = (col < 1024) ? (o0 + (size_t)col * 16384 + row)
                                : (o1 + (size_t)(col - 1024) * 16384 + row);
        *(ushort4*)dst = make_ushort4(f2b(v.x + bias), f2b(v.y + bias), f2b(v.z + bias), f2b(v.w + bias));
      } else if constexpr (EPI == EPI_PV) {
        const u16* gt = o1 + (size_t)col * 16384 + (size_t)bat * 4096 + row;
        ushort4 g = *(const ushort4*)gt;
        u16* dst = o0 + (size_t)bat * 4096 * 1024;
        dst[(size_t)(row + 0) * 1024 + col] = f2b(v.x * b2f(g.x));
        dst[(size_t)(row + 1) * 1024 + col] = f2b(v.y * b2f(g.y));
        dst[(size_t)(row + 2) * 1024 + col] = f2b(v.z * b2f(g.z));
        dst[(size_t)(row + 3) * 1024 + col] = f2b(v.w * b2f(g.w));
      }
    }
  }
}

// ---------- lean single-stage ATTN (K=128 staged once) ----------
// C[j][q] = K . Q^T (swapped); relu^2(scale*) -> attn[q][j] bf16.
// 512 thr, 8 waves (2j x 4q); LDS: A(K) 64K @0, B(Q) 64K @64K; rows 256B.
__device__ __forceinline__ void stage256(char* s, const char* g, int tid) {
#pragma unroll
  for (int i = 0; i < 8; ++i) {
    int o = (i * 512 + tid) * 16;
    int row = o >> 8;
    int cb = o & 255;
    int scb = cb ^ ((row & 7) << 4);
    __builtin_amdgcn_global_load_lds((const __attribute__((address_space(1))) void*)(g + (long)row * 256 + scb),
                                     (__attribute__((address_space(3))) void*)(s + o), 16, 0, 0);
  }
}

__global__ __launch_bounds__(512, 2) void attn_lean(
    const char* Kb, const char* Qb, u16* o0, int nx) {
  extern __shared__ __align__(16) char lds[];
  const int tid = threadIdx.x;
  const int lane = tid & 63;
  const int wave = tid >> 6;
  const int wm = wave >> 2;        // j half
  const int wn = wave & 3;         // q quarter
  const int l16 = lane & 15, lq = lane >> 4;
  const int bat = blockIdx.y;

  const int nwg = gridDim.x;       // 256 (%8==0)
  const int qq = nwg >> 3;
  const int fid = blockIdx.x;
  const int swz = (fid & 7) * qq + (fid >> 3);
  const int row0 = (swz / nx) * 256;   // j
  const int col0 = (swz % nx) * 256;   // q

  const char* gA = Kb + (size_t)bat * 4096 * 256 + (size_t)row0 * 256;
  const char* gB = Qb + (size_t)bat * 4096 * 256 + (size_t)col0 * 256;

  stage256(lds, gA, tid);
  stage256(lds + 65536, gB, tid);
  VMCNT0();
  BAR();

  const char* myA = lds + wm * 32768;                 // 128 j-rows x 256B
  const char* myB = lds + 65536 + (wn >> 1) * 32768;  // 128 q-rows x 256B
  const int rB = (wn & 1) * 64;
  const int kmask = (l16 & 7) << 4;

  f32x4 acc[8][4];
#pragma unroll
  for (int i = 0; i < 8; ++i)
#pragma unroll
    for (int j = 0; j < 4; ++j) acc[i][j] = (f32x4){0.f, 0.f, 0.f, 0.f};

#pragma unroll
  for (int kk = 0; kk < 4; ++kk) {
    const int kb = (kk * 64 + lq * 16) ^ kmask;
    bf16x8 a[8], b[4];
#pragma unroll
    for (int mf = 0; mf < 8; ++mf)
      a[mf] = *(const bf16x8*)(myA + (mf * 16 + l16) * 256 + kb);
#pragma unroll
    for (int nf = 0; nf < 4; ++nf)
      b[nf] = *(const bf16x8*)(myB + (rB + nf * 16 + l16) * 256 + kb);
    __builtin_amdgcn_s_setprio(1);
#pragma unroll
    for (int mf = 0; mf < 8; ++mf)
#pragma unroll
      for (int nf = 0; nf < 4; ++nf)
        acc[mf][nf] = __builtin_amdgcn_mfma_f32_16x16x32_bf16(a[mf], b[nf], acc[mf][nf], 0, 0, 0);
    __builtin_amdgcn_s_setprio(0);
  }

  const float scale = 0.088388347648318447f;  // 128^-0.5
  u16* dst = o0 + (size_t)bat * 4096 * 4096;
#pragma unroll
  for (int mi = 0; mi < 8; ++mi) {
#pragma unroll
    for (int ni = 0; ni < 4; ++ni) {
      const int row = row0 + wm * 128 + mi * 16 + lq * 4;   // j (4 consecutive)
      const int col = col0 + wn * 64 + ni * 16 + l16;       // q
      f32x4 v = acc[mi][ni];
      float t0 = v.x * scale; t0 = t0 > 0.f ? t0 * t0 : 0.f;
      float t1 = v.y * scale; t1 = t1 > 0.f ? t1 * t1 : 0.f;
      float t2 = v.z * scale; t2 = t2 > 0.f ? t2 * t2 : 0.f;
      float t3 = v.w * scale; t3 = t3 > 0.f ? t3 * t3 : 0.f;
      *(ushort4*)(dst + (size_t)col * 4096 + row) =
          make_ushort4(f2b(t0), f2b(t1), f2b(t2), f2b(t3));
    }
  }
}

__global__ void conv_b(const float* in, u16* out, int n) {
  int i = (blockIdx.x * blockDim.x + threadIdx.x) * 4;
  if (i >= n) return;
  float4 f = *(const float4*)(in + i);
  *(ushort4*)(out + i) = make_ushort4(f2b(f.x), f2b(f.y), f2b(f.z), f2b(f.w));
}

// out[c][r] = bf16(in[r][c]) via LDS 32x32 tile (+1 pad) — both sides coalesced
__global__ void transpose_lds(const float* in, u16* out, int R, int C) {
  __shared__ float t[32][33];
  const int tx = threadIdx.x & 31, ty = threadIdx.x >> 5;  // 32x8
  const int c0 = blockIdx.x * 32, r0 = blockIdx.y * 32;
#pragma unroll
  for (int i = 0; i < 32; i += 8)
    t[ty + i][tx] = in[(size_t)(r0 + ty + i) * C + c0 + tx];
  __syncthreads();
#pragma unroll
  for (int i = 0; i < 32; i += 8)
    out[(size_t)(c0 + ty + i) * R + r0 + tx] = f2b(t[tx][ty + i]);
}

extern "C" void kernel_launch(void* const* d_in, const int* in_sizes, int n_in,
                              void* d_out, int out_size, void* d_ws, size_t ws_size,
                              hipStream_t stream) {
  const float* x = (const float*)d_in[0];
  const float* w_hidden = (const float*)d_in[1];
  const float* b_hidden = (const float*)d_in[2];
  const float* w_qk = (const float*)d_in[3];
  const float* q_gamma = (const float*)d_in[4];
  const float* q_beta = (const float*)d_in[5];
  const float* k_gamma = (const float*)d_in[6];
  const float* k_beta = (const float*)d_in[7];
  const float* w_out = (const float*)d_in[8];
  const float* b_out = (const float*)d_in[9];
  float* out = (float*)d_out;

  char* ws = (char*)d_ws;
  size_t off = 0;
  auto alloc = [&](size_t bytes) { char* p = ws + off; off += (bytes + 255) & ~255ull; return p; };
  u16* xb     = (u16*)alloc(16384ull * 512 * 2);
  u16* wh_t   = (u16*)alloc(2048ull * 512 * 2);
  u16* wqk_t  = (u16*)alloc(128ull * 512 * 2);
  u16* wout_t = (u16*)alloc(512ull * 1024 * 2);
  u16* v_t    = (u16*)alloc(1024ull * 16384 * 2);
  u16* g_t    = (u16*)alloc(1024ull * 16384 * 2);
  u16* qb_a   = (u16*)alloc(16384ull * 128 * 2);
  u16* kb_a   = (u16*)alloc(16384ull * 128 * 2);
  u16* attnb  = (u16*)alloc(4ull * 4096 * 4096 * 2);
  u16* out1b  = (u16*)alloc(16384ull * 1024 * 2);

  (void)hipFuncSetAttribute((const void*)gemm256<EPI_HID>, hipFuncAttributeMaxDynamicSharedMemorySize, 131072);
  (void)hipFuncSetAttribute((const void*)gemm256<EPI_PV>, hipFuncAttributeMaxDynamicSharedMemorySize, 131072);
  (void)hipFuncSetAttribute((const void*)attn_lean, hipFuncAttributeMaxDynamicSharedMemorySize, 131072);

  conv_b<<<(16384 * 512 / 4 + 255) / 256, 256, 0, stream>>>(x, xb, 16384 * 512);
  transpose_lds<<<dim3(2048 / 32, 512 / 32), 256, 0, stream>>>(w_hidden, wh_t, 512, 2048);
  transpose_lds<<<dim3(128 / 32, 512 / 32), 256, 0, stream>>>(w_qk, wqk_t, 512, 128);
  transpose_lds<<<dim3(512 / 32, 1024 / 32), 256, 0, stream>>>(w_out, wout_t, 1024, 512);

  // GEMM1: hid = x @ Wh (+bias) -> v_t, g_t (transposed bf16). M=16384 N=2048 K=512
  gemm256<EPI_HID><<<dim3(512, 1), 512, 131072, stream>>>(
      (const char*)xb, (const char*)wh_t, 0, 0, 1024, 1024, 8, 8,
      v_t, g_t, b_hidden, nullptr, nullptr);
  // GEMM2: qk = x @ Wqk -> q,k (offset-scale). N=128
  gemm_tn<EPI_QK><<<dim3(1, 128, 1), 256, 0, stream>>>(
      (const char*)xb, (const char*)wqk_t, 0, 0, 1024, 1024, 8,
      qb_a, kb_a, q_gamma, q_beta, k_gamma, k_beta, nullptr, nullptr);
  // sim: C[j][q] = K @ Q^T, relu^2(scale*) -> attn[q][j] bf16 (lean single-stage)
  attn_lean<<<dim3(256, 4), 512, 131072, stream>>>(
      (const char*)kb_a, (const char*)qb_a, attnb, 16);
  // out1 = (attn @ v) * gate. per batch M=4096 N=1024 K=4096
  gemm256<EPI_PV><<<dim3(64, 4), 512, 131072, stream>>>(
      (const char*)attnb, (const char*)v_t, 4096ll * 8192, 8192, 8192, 32768, 64, 4,
      out1b, g_t, nullptr, nullptr, nullptr);
  // out = out1 @ Wout + b_out + x. M=16384 N=512 K=1024
  gemm_tn<EPI_OUT><<<dim3(4, 128, 1), 256, 0, stream>>>(
      (const char*)out1b, (const char*)wout_t, 0, 0, 2048, 2048, 16,
      nullptr, nullptr, b_out, nullptr, nullptr, nullptr, out, x);
}

// Round 12
// 314.680 us; speedup vs baseline: 1.4942x; 1.0058x over previous
//
#include <hip/hip_runtime.h>
#include <hip/hip_bf16.h>

typedef __attribute__((ext_vector_type(8))) short bf16x8;
typedef __attribute__((ext_vector_type(4))) float f32x4;
typedef unsigned short u16;

__device__ __forceinline__ u16 f2b(float f) {
  __hip_bfloat16 h = __float2bfloat16(f);
  return __builtin_bit_cast(unsigned short, h);
}
__device__ __forceinline__ float b2f(u16 u) {
  __hip_bfloat16 h = __builtin_bit_cast(__hip_bfloat16, u);
  return __bfloat162float(h);
}

#define BAR() __builtin_amdgcn_s_barrier()
#define LGKM0() do { asm volatile("s_waitcnt lgkmcnt(0)" ::: "memory"); __builtin_amdgcn_sched_barrier(0); } while (0)
#define LGKM4() do { asm volatile("s_waitcnt lgkmcnt(4)" ::: "memory"); __builtin_amdgcn_sched_barrier(0); } while (0)
#define LGKM8() do { asm volatile("s_waitcnt lgkmcnt(8)" ::: "memory"); __builtin_amdgcn_sched_barrier(0); } while (0)
#define VMCNT4() asm volatile("s_waitcnt vmcnt(4)" ::: "memory")
#define VMCNT2() asm volatile("s_waitcnt vmcnt(2)" ::: "memory")
#define VMCNT0() asm volatile("s_waitcnt vmcnt(0)" ::: "memory")

#define EPI_HID 0
#define EPI_QK 1
#define EPI_PV 3
#define EPI_OUT 4

// ---------- 128^2 2-phase kernel (QK: N=128; OUT: N=512) ----------
__device__ __forceinline__ void stage_tile(char* sbase, const char* gbase, int ld_bytes, int tid) {
#pragma unroll
  for (int i = 0; i < 4; ++i) {
    int o = (i * 256 + tid) * 16;
    int row = o >> 7;
    int cb = o & 127;
    int scb = cb ^ ((row & 7) << 4);
    const char* src = gbase + (long)row * ld_bytes + scb;
    __builtin_amdgcn_global_load_lds((const __attribute__((address_space(1))) void*)src,
                                     (__attribute__((address_space(3))) void*)(sbase + o),
                                     16, 0, 0);
  }
}

template <int EPI>
__global__ __launch_bounds__(256, 2) void gemm_tn(
    const char* Ab, const char* Bb, long sAbat, long sBbat,
    int lda_b, int ldb_b, int nkt,
    u16* o0, u16* o1,
    const float* a0, const float* a1, const float* a2, const float* a3,
    float* fout, const float* xres) {
  __shared__ __align__(16) char lds[32768];
  char* sA = lds;
  char* sB = lds + 16384;
  const int tid = threadIdx.x;
  const int lane = tid & 63;
  const int wave = tid >> 6;
  const int wm = wave >> 1, wn = wave & 1;
  const int l16 = lane & 15, lq = lane >> 4;
  const int bat = blockIdx.z;
  const int row0 = blockIdx.y * 128;
  const int col0 = blockIdx.x * 128;

  const char* Abase = Ab + (long)bat * sAbat + (long)row0 * lda_b;
  const char* Bbase = Bb + (long)bat * sBbat + (long)col0 * ldb_b;

  f32x4 acc[4][4];
#pragma unroll
  for (int i = 0; i < 4; ++i)
#pragma unroll
    for (int j = 0; j < 4; ++j) acc[i][j] = (f32x4){0.f, 0.f, 0.f, 0.f};

  for (int kt = 0; kt < nkt; ++kt) {
    stage_tile(sA, Abase + (long)kt * 128, lda_b, tid);
    stage_tile(sB, Bbase + (long)kt * 128, ldb_b, tid);
    __syncthreads();
#pragma unroll
    for (int kk = 0; kk < 2; ++kk) {
      bf16x8 af[4], bfr[4];
#pragma unroll
      for (int mf = 0; mf < 4; ++mf) {
        int r = wm * 64 + mf * 16 + l16;
        int kb = kk * 64 + lq * 16;
        af[mf] = *(const bf16x8*)(sA + r * 128 + (kb ^ ((r & 7) << 4)));
      }
#pragma unroll
      for (int nf = 0; nf < 4; ++nf) {
        int r = wn * 64 + nf * 16 + l16;
        int kb = kk * 64 + lq * 16;
        bfr[nf] = *(const bf16x8*)(sB + r * 128 + (kb ^ ((r & 7) << 4)));
      }
#pragma unroll
      for (int mf = 0; mf < 4; ++mf)
#pragma unroll
        for (int nf = 0; nf < 4; ++nf)
          acc[mf][nf] = __builtin_amdgcn_mfma_f32_16x16x32_bf16(af[mf], bfr[nf], acc[mf][nf], 0, 0, 0);
    }
    __syncthreads();
  }

#pragma unroll
  for (int mf = 0; mf < 4; ++mf) {
#pragma unroll
    for (int nf = 0; nf < 4; ++nf) {
      const int row = row0 + wm * 64 + mf * 16 + lq * 4;
      const int col = col0 + wn * 64 + nf * 16 + l16;
      f32x4 v = acc[mf][nf];
      if constexpr (EPI == EPI_QK) {
        float qg = a0[col], qbt = a1[col], kg = a2[col], kbt = a3[col];
#pragma unroll
        for (int i = 0; i < 4; ++i) {
          float t = v[i];
          o0[(size_t)(row + i) * 128 + col] = f2b(t * qg + qbt);
          o1[(size_t)(row + i) * 128 + col] = f2b(t * kg + kbt);
        }
      } else if constexpr (EPI == EPI_OUT) {
        float bias = a0[col];
#pragma unroll
        for (int i = 0; i < 4; ++i)
          fout[(size_t)(row + i) * 512 + col] = v[i] + bias + xres[(size_t)(row + i) * 512 + col];
      }
    }
  }
}

// ---------- 256^2 16x16 minimal-barrier kernel (HID, PV) ----------
// LDS forces 1 block/CU; launch_bounds(512,1) frees VGPR headroom (no occupancy cost).
__device__ __forceinline__ void stage_half(char* sbase, const char* gbase, long ld, int tid) {
#pragma unroll
  for (int i = 0; i < 2; ++i) {
    int o = (i * 512 + tid) * 16;
    int row = o >> 7;
    int cb = o & 127;
    int scb = cb ^ ((row & 7) << 4);
    const char* src = gbase + (long)row * ld + scb;
    __builtin_amdgcn_global_load_lds((const __attribute__((address_space(1))) void*)src,
                                     (__attribute__((address_space(3))) void*)(sbase + o),
                                     16, 0, 0);
  }
}

template <int EPI>
__global__ __launch_bounds__(512, 1) void gemm256(
    const char* Ab, const char* Bb, long sAbat, long sBbat,
    long lda, long ldb, int nkt, int nx,
    u16* o0, u16* o1,
    const float* a0, float* fout, const float* xres) {
  extern __shared__ __align__(16) char lds[];
  const int tid = threadIdx.x;
  const int lane = tid & 63;
  const int wave = tid >> 6;
  const int wm = wave >> 2;
  const int wn = wave & 3;
  const int l16 = lane & 15, lq = lane >> 4;
  const int bat = blockIdx.y;

  const int nwg = gridDim.x;
  const int qq = nwg >> 3;
  const int fid = blockIdx.x;
  const int swz = (fid & 7) * qq + (fid >> 3);
  const int row0 = (swz / nx) * 256;
  const int col0 = (swz % nx) * 256;

  const char* gA = Ab + (long)bat * sAbat + (long)row0 * lda;
  const char* gB = Bb + (long)bat * sBbat + (long)col0 * ldb;

  f32x4 acc[8][4];
#pragma unroll
  for (int i = 0; i < 8; ++i)
#pragma unroll
    for (int j = 0; j < 4; ++j) acc[i][j] = (f32x4){0.f, 0.f, 0.f, 0.f};

  const int kmask = (l16 & 7) << 4;
  const int kb0 = (lq * 16) ^ kmask;
  const int kb1 = (64 + lq * 16) ^ kmask;
  const int rB = (wn & 1) * 64;

  stage_half(lds + 32768, gB, ldb, tid);
  stage_half(lds + 32768 + 16384, gB + 128 * ldb, ldb, tid);
  stage_half(lds, gA, lda, tid);
  stage_half(lds + 16384, gA + 128 * lda, lda, tid);
  if (nkt > 1) {
    stage_half(lds + 65536 + 32768, gB + 128, ldb, tid);
    stage_half(lds + 65536 + 32768 + 16384, gB + 128 * ldb + 128, ldb, tid);
    VMCNT4();
  } else {
    VMCNT0();
  }
  BAR();

  bf16x8 af0[4], af1[4], afp0[4], afp1[4], bfr0[4], bfr1[4];
  {
    const char* myA = lds + wm * 16384;
    const char* myB = lds + 32768 + (wn >> 1) * 16384;
#pragma unroll
    for (int nf = 0; nf < 4; ++nf)
      bfr0[nf] = *(const bf16x8*)(myB + (rB + nf * 16 + l16) * 128 + kb0);
#pragma unroll
    for (int mf = 0; mf < 4; ++mf)
      af0[mf] = *(const bf16x8*)(myA + (mf * 16 + l16) * 128 + kb0);
  }

  for (int t = 0; t < nkt; ++t) {
    const char* bufc = lds + (t & 1) * 65536;
    const char* bufn = lds + ((t + 1) & 1) * 65536;
    const char* myA = bufc + wm * 16384;
    const char* myB = bufc + 32768 + (wn >> 1) * 16384;
    const char* nA = bufn + wm * 16384;
    const char* nB = bufn + 32768 + (wn >> 1) * 16384;
    char* stA = (char*)bufn;
    char* stB = (char*)bufc + 32768;
    const bool sA_ok = (t + 1) < nkt;
    const bool sB_ok = (t + 2) < nkt;

#pragma unroll
    for (int nf = 0; nf < 4; ++nf)
      bfr1[nf] = *(const bf16x8*)(myB + (rB + nf * 16 + l16) * 128 + kb1);
#pragma unroll
    for (int mf = 0; mf < 4; ++mf)
      af1[mf] = *(const bf16x8*)(myA + (mf * 16 + l16) * 128 + kb1);
    if (sA_ok) stage_half(stA, gA + (long)(t + 1) * 128, lda, tid);
    LGKM8();
    __builtin_amdgcn_s_setprio(1);
#pragma unroll
    for (int mf = 0; mf < 4; ++mf)
#pragma unroll
      for (int nf = 0; nf < 4; ++nf)
        acc[mf][nf] = __builtin_amdgcn_mfma_f32_16x16x32_bf16(af0[mf], bfr0[nf], acc[mf][nf], 0, 0, 0);
    __builtin_amdgcn_s_setprio(0);

#pragma unroll
    for (int mf = 0; mf < 4; ++mf)
      afp0[mf] = *(const bf16x8*)(myA + (64 + mf * 16 + l16) * 128 + kb0);
    if (sA_ok) stage_half(stA + 16384, gA + 128 * lda + (long)(t + 1) * 128, lda, tid);
    LGKM4();
    __builtin_amdgcn_s_setprio(1);
#pragma unroll
    for (int mf = 0; mf < 4; ++mf)
#pragma unroll
      for (int nf = 0; nf < 4; ++nf)
        acc[mf][nf] = __builtin_amdgcn_mfma_f32_16x16x32_bf16(af1[mf], bfr1[nf], acc[mf][nf], 0, 0, 0);
    __builtin_amdgcn_s_setprio(0);
    BAR();

#pragma unroll
    for (int mf = 0; mf < 4; ++mf)
      afp1[mf] = *(const bf16x8*)(myA + (64 + mf * 16 + l16) * 128 + kb1);
    if (sB_ok) stage_half(stB, gB + (long)(t + 2) * 128, ldb, tid);
    LGKM4();
    __builtin_amdgcn_s_setprio(1);
#pragma unroll
    for (int mf = 0; mf < 4; ++mf)
#pragma unroll
      for (int nf = 0; nf < 4; ++nf)
        acc[4 + mf][nf] = __builtin_amdgcn_mfma_f32_16x16x32_bf16(afp0[mf], bfr0[nf], acc[4 + mf][nf], 0, 0, 0);
    __builtin_amdgcn_s_setprio(0);
    if (sA_ok) {
      if (sB_ok) { VMCNT2(); } else { VMCNT0(); }
      BAR();
    }

    if (sA_ok) {
#pragma unroll
      for (int nf = 0; nf < 4; ++nf)
        bfr0[nf] = *(const bf16x8*)(nB + (rB + nf * 16 + l16) * 128 + kb0);
#pragma unroll
      for (int mf = 0; mf < 4; ++mf)
        af0[mf] = *(const bf16x8*)(nA + (mf * 16 + l16) * 128 + kb0);
    }
    if (sB_ok) stage_half(stB + 16384, gB + 128 * ldb + (long)(t + 2) * 128, ldb, tid);
    if (sA_ok) { LGKM8(); } else { LGKM0(); }
    __builtin_amdgcn_s_setprio(1);
#pragma unroll
    for (int mf = 0; mf < 4; ++mf)
#pragma unroll
      for (int nf = 0; nf < 4; ++nf)
        acc[4 + mf][nf] = __builtin_amdgcn_mfma_f32_16x16x32_bf16(afp1[mf], bfr1[nf], acc[4 + mf][nf], 0, 0, 0);
    __builtin_amdgcn_s_setprio(0);
    BAR();
  }

  // epilogue
#pragma unroll
  for (int mi = 0; mi < 8; ++mi) {
#pragma unroll
    for (int ni = 0; ni < 4; ++ni) {
      const int row = row0 + wm * 128 + mi * 16 + lq * 4;
      const int col = col0 + wn * 64 + ni * 16 + l16;
      f32x4 v = acc[mi][ni];
      if constexpr (EPI == EPI_HID) {
        float bias = a0[col];
        u16* dst = (col < 1024) ? (o0 + (size_t)col * 16384 + row)
                                : (o1 + (size_t)(col - 1024) * 16384 + row);
        *(ushort4*)dst = make_ushort4(f2b(v.x + bias), f2b(v.y + bias), f2b(v.z + bias), f2b(v.w + bias));
      } else if constexpr (EPI == EPI_PV) {
        const u16* gt = o1 + (size_t)col * 16384 + (size_t)bat * 4096 + row;
        ushort4 g = *(const ushort4*)gt;
        u16* dst = o0 + (size_t)bat * 4096 * 1024;
        dst[(size_t)(row + 0) * 1024 + col] = f2b(v.x * b2f(g.x));
        dst[(size_t)(row + 1) * 1024 + col] = f2b(v.y * b2f(g.y));
        dst[(size_t)(row + 2) * 1024 + col] = f2b(v.z * b2f(g.z));
        dst[(size_t)(row + 3) * 1024 + col] = f2b(v.w * b2f(g.w));
      }
    }
  }
}

// ---------- lean single-stage ATTN (K=128 staged once), software-pipelined ----------
// C[j][q] = K . Q^T (swapped); relu^2(scale*) -> attn[q][j] bf16.
// 512 thr, 8 waves (2j x 4q); LDS: A(K) 64K @0, B(Q) 64K @64K; rows 256B.
// launch_bounds(512,1): LDS already caps at 1 block/CU; free VGPRs let the
// k-step k+1 fragment loads (12 x b128) fly under step k's 32 MFMAs.
__device__ __forceinline__ void stage256(char* s, const char* g, int tid) {
#pragma unroll
  for (int i = 0; i < 8; ++i) {
    int o = (i * 512 + tid) * 16;
    int row = o >> 8;
    int cb = o & 255;
    int scb = cb ^ ((row & 7) << 4);
    __builtin_amdgcn_global_load_lds((const __attribute__((address_space(1))) void*)(g + (long)row * 256 + scb),
                                     (__attribute__((address_space(3))) void*)(s + o), 16, 0, 0);
  }
}

__global__ __launch_bounds__(512, 1) void attn_lean(
    const char* Kb, const char* Qb, u16* o0, int nx) {
  extern __shared__ __align__(16) char lds[];
  const int tid = threadIdx.x;
  const int lane = tid & 63;
  const int wave = tid >> 6;
  const int wm = wave >> 2;        // j half
  const int wn = wave & 3;         // q quarter
  const int l16 = lane & 15, lq = lane >> 4;
  const int bat = blockIdx.y;

  const int nwg = gridDim.x;       // 256 (%8==0)
  const int qq = nwg >> 3;
  const int fid = blockIdx.x;
  const int swz = (fid & 7) * qq + (fid >> 3);
  const int row0 = (swz / nx) * 256;   // j
  const int col0 = (swz % nx) * 256;   // q

  const char* gA = Kb + (size_t)bat * 4096 * 256 + (size_t)row0 * 256;
  const char* gB = Qb + (size_t)bat * 4096 * 256 + (size_t)col0 * 256;

  stage256(lds, gA, tid);
  stage256(lds + 65536, gB, tid);
  VMCNT0();
  BAR();

  const char* myA = lds + wm * 32768;                 // 128 j-rows x 256B
  const char* myB = lds + 65536 + (wn >> 1) * 32768;  // 128 q-rows x 256B
  const int rB = (wn & 1) * 64;
  const int kmask = (l16 & 7) << 4;

  f32x4 acc[8][4];
#pragma unroll
  for (int i = 0; i < 8; ++i)
#pragma unroll
    for (int j = 0; j < 4; ++j) acc[i][j] = (f32x4){0.f, 0.f, 0.f, 0.f};

  bf16x8 aC[8], bC[4], aN[8], bN[4];

#define LOADK(A, B, kk)                                                        \
  do {                                                                         \
    const int kb_ = ((kk) * 64 + lq * 16) ^ kmask;                             \
    _Pragma("unroll") for (int mf = 0; mf < 8; ++mf)                           \
        A[mf] = *(const bf16x8*)(myA + (mf * 16 + l16) * 256 + kb_);           \
    _Pragma("unroll") for (int nf = 0; nf < 4; ++nf)                           \
        B[nf] = *(const bf16x8*)(myB + (rB + nf * 16 + l16) * 256 + kb_);      \
  } while (0)
#define MMK(A, B)                                                              \
  do {                                                                         \
    _Pragma("unroll") for (int mf = 0; mf < 8; ++mf)                           \
        _Pragma("unroll") for (int nf = 0; nf < 4; ++nf)                       \
            acc[mf][nf] =                                                      \
        __builtin_amdgcn_mfma_f32_16x16x32_bf16(A[mf], B[nf], acc[mf][nf], 0, 0, 0); \
  } while (0)

  LOADK(aC, bC, 0);
  LOADK(aN, bN, 1);
  MMK(aC, bC);
  LOADK(aC, bC, 2);
  MMK(aN, bN);
  LOADK(aN, bN, 3);
  MMK(aC, bC);
  MMK(aN, bN);
#undef LOADK
#undef MMK

  const float scale = 0.088388347648318447f;  // 128^-0.5
  u16* dst = o0 + (size_t)bat * 4096 * 4096;
#pragma unroll
  for (int mi = 0; mi < 8; ++mi) {
#pragma unroll
    for (int ni = 0; ni < 4; ++ni) {
      const int row = row0 + wm * 128 + mi * 16 + lq * 4;   // j (4 consecutive)
      const int col = col0 + wn * 64 + ni * 16 + l16;       // q
      f32x4 v = acc[mi][ni];
      float t0 = v.x * scale; t0 = t0 > 0.f ? t0 * t0 : 0.f;
      float t1 = v.y * scale; t1 = t1 > 0.f ? t1 * t1 : 0.f;
      float t2 = v.z * scale; t2 = t2 > 0.f ? t2 * t2 : 0.f;
      float t3 = v.w * scale; t3 = t3 > 0.f ? t3 * t3 : 0.f;
      *(ushort4*)(dst + (size_t)col * 4096 + row) =
          make_ushort4(f2b(t0), f2b(t1), f2b(t2), f2b(t3));
    }
  }
}

__global__ void conv_b(const float* in, u16* out, int n) {
  int i = (blockIdx.x * blockDim.x + threadIdx.x) * 4;
  if (i >= n) return;
  float4 f = *(const float4*)(in + i);
  *(ushort4*)(out + i) = make_ushort4(f2b(f.x), f2b(f.y), f2b(f.z), f2b(f.w));
}

// out[c][r] = bf16(in[r][c]) via LDS 32x32 tile (+1 pad) — both sides coalesced
__global__ void transpose_lds(const float* in, u16* out, int R, int C) {
  __shared__ float t[32][33];
  const int tx = threadIdx.x & 31, ty = threadIdx.x >> 5;  // 32x8
  const int c0 = blockIdx.x * 32, r0 = blockIdx.y * 32;
#pragma unroll
  for (int i = 0; i < 32; i += 8)
    t[ty + i][tx] = in[(size_t)(r0 + ty + i) * C + c0 + tx];
  __syncthreads();
#pragma unroll
  for (int i = 0; i < 32; i += 8)
    out[(size_t)(c0 + ty + i) * R + r0 + tx] = f2b(t[tx][ty + i]);
}

extern "C" void kernel_launch(void* const* d_in, const int* in_sizes, int n_in,
                              void* d_out, int out_size, void* d_ws, size_t ws_size,
                              hipStream_t stream) {
  const float* x = (const float*)d_in[0];
  const float* w_hidden = (const float*)d_in[1];
  const float* b_hidden = (const float*)d_in[2];
  const float* w_qk = (const float*)d_in[3];
  const float* q_gamma = (const float*)d_in[4];
  const float* q_beta = (const float*)d_in[5];
  const float* k_gamma = (const float*)d_in[6];
  const float* k_beta = (const float*)d_in[7];
  const float* w_out = (const float*)d_in[8];
  const float* b_out = (const float*)d_in[9];
  float* out = (float*)d_out;

  char* ws = (char*)d_ws;
  size_t off = 0;
  auto alloc = [&](size_t bytes) { char* p = ws + off; off += (bytes + 255) & ~255ull; return p; };
  u16* xb     = (u16*)alloc(16384ull * 512 * 2);
  u16* wh_t   = (u16*)alloc(2048ull * 512 * 2);
  u16* wqk_t  = (u16*)alloc(128ull * 512 * 2);
  u16* wout_t = (u16*)alloc(512ull * 1024 * 2);
  u16* v_t    = (u16*)alloc(1024ull * 16384 * 2);
  u16* g_t    = (u16*)alloc(1024ull * 16384 * 2);
  u16* qb_a   = (u16*)alloc(16384ull * 128 * 2);
  u16* kb_a   = (u16*)alloc(16384ull * 128 * 2);
  u16* attnb  = (u16*)alloc(4ull * 4096 * 4096 * 2);
  u16* out1b  = (u16*)alloc(16384ull * 1024 * 2);

  (void)hipFuncSetAttribute((const void*)gemm256<EPI_HID>, hipFuncAttributeMaxDynamicSharedMemorySize, 131072);
  (void)hipFuncSetAttribute((const void*)gemm256<EPI_PV>, hipFuncAttributeMaxDynamicSharedMemorySize, 131072);
  (void)hipFuncSetAttribute((const void*)attn_lean, hipFuncAttributeMaxDynamicSharedMemorySize, 131072);

  conv_b<<<(16384 * 512 / 4 + 255) / 256, 256, 0, stream>>>(x, xb, 16384 * 512);
  transpose_lds<<<dim3(2048 / 32, 512 / 32), 256, 0, stream>>>(w_hidden, wh_t, 512, 2048);
  transpose_lds<<<dim3(128 / 32, 512 / 32), 256, 0, stream>>>(w_qk, wqk_t, 512, 128);
  transpose_lds<<<dim3(512 / 32, 1024 / 32), 256, 0, stream>>>(w_out, wout_t, 1024, 512);

  // GEMM1: hid = x @ Wh (+bias) -> v_t, g_t (transposed bf16). M=16384 N=2048 K=512
  gemm256<EPI_HID><<<dim3(512, 1), 512, 131072, stream>>>(
      (const char*)xb, (const char*)wh_t, 0, 0, 1024, 1024, 8, 8,
      v_t, g_t, b_hidden, nullptr, nullptr);
  // GEMM2: qk = x @ Wqk -> q,k (offset-scale). N=128
  gemm_tn<EPI_QK><<<dim3(1, 128, 1), 256, 0, stream>>>(
      (const char*)xb, (const char*)wqk_t, 0, 0, 1024, 1024, 8,
      qb_a, kb_a, q_gamma, q_beta, k_gamma, k_beta, nullptr, nullptr);
  // sim: C[j][q] = K @ Q^T, relu^2(scale*) -> attn[q][j] bf16 (lean single-stage)
  attn_lean<<<dim3(256, 4), 512, 131072, stream>>>(
      (const char*)kb_a, (const char*)qb_a, attnb, 16);
  // out1 = (attn @ v) * gate. per batch M=4096 N=1024 K=4096
  gemm256<EPI_PV><<<dim3(64, 4), 512, 131072, stream>>>(
      (const char*)attnb, (const char*)v_t, 4096ll * 8192, 8192, 8192, 32768, 64, 4,
      out1b, g_t, nullptr, nullptr, nullptr);
  // out = out1 @ Wout + b_out + x. M=16384 N=512 K=1024
  gemm_tn<EPI_OUT><<<dim3(4, 128, 1), 256, 0, stream>>>(
      (const char*)out1b, (const char*)wout_t, 0, 0, 2048, 2048, 16,
      nullptr, nullptr, b_out, nullptr, nullptr, nullptr, out, x);
}